// Round 7
// baseline (137.454 us; speedup 1.0000x reference)
//
#include <hip/hip_runtime.h>

// ---------------------------------------------------------------------------
// DeepLagrangianNetwork head — round 11: R9 skeleton + MFMA heads + 5 blk/CU.
// Ledger: every round so far ran at <=4 waves/SIMD and landed 51-65 us;
// occupancy >4/SIMD is the unpulled lever. R10 (all-MFMA) cut issue but cost
// VGPR 132 -> 3 waves/SIMD -> slower. This round:
//   - R9's verified structure: phase-1 VALU h1 (one row/lane, cvt_pk, LDS),
//     layer-2 MFMA from LDS h1 fragments. 32 KiB LDS, zero barriers.
//   - Heads via MFMA: layer-2 A uses nu-permuted W2 rows,
//       nu(mt,m) = 32*(mt>>1) + 8*(m>>2) + 4*(mt&1) + (m&3),
//     so the lrelu'd, cvt_pk-packed C output IS the head-MFMA B fragment
//     with neuron k in k-slot k (identity handoff; same trick R10 verified
//     for layer1->layer2). b2 init uses the same permutation (contiguous
//     f32x4: b2 + 32*(mt>>1) + 4*(mt&1) + 8*quad).
//     Head A = [WLd row0; WLd row1; WLo; 0...] with hi/lo bf16 split
//     (4 MFMAs) -> head weights effectively fp32-exact; h2 enters heads as
//     bf16 (same as the original 130us baseline's verified numerics).
//     Deletes 48 VGPRs of head weights + 24 pk-FMA + 6 shuffles + select/it.
//   - grid 1280 = 5 blocks/CU (LDS 32 KiB x 5 = 160 KiB exactly), single
//     generation, grid-stride; target 20 waves/CU (5/SIMD) with VGPR <= 102.
// NO launch_bounds min-waves clause (clamps to 64 VGPR + spills; rounds 6,8).
// Fragment layouts (m89/m120-verified):
//   A[m=lane&15][k=(lane>>4)*8+j]   B[k=(lane>>4)*8+j][n=lane&15]
//   C: col(n)=lane&15, row(m)=(lane>>4)*4+reg
// ---------------------------------------------------------------------------

typedef __attribute__((ext_vector_type(8))) short bf16x8;
typedef __attribute__((ext_vector_type(4))) float f32x4;
typedef __attribute__((ext_vector_type(2))) float f32x2;

#define BLOCK_THREADS  256      // 4 waves
#define GRID_BLOCKS    1280     // 5 blocks/CU on 256 CUs — single generation
#define ROWS_PER_GROUP 256

__device__ __forceinline__ float lrelu(float a) {
    return fmaxf(a, 0.01f * a);     // exact leaky_relu(0.01)
}

__device__ __forceinline__ f32x2 lrelu2(f32x2 a) {
    return __builtin_elementwise_max(a, a * 0.01f);
}

__device__ __forceinline__ float softplus(float v) {
    return fmaxf(v, 0.0f) + log1pf(expf(-fabsf(v)));   // jax.nn.softplus
}

// two fp32 -> packed bf16x2 (hardware RNE), 1 VALU op.
__device__ __forceinline__ unsigned cvt_pk_bf16(float lo, float hi) {
    unsigned r;
    asm("v_cvt_pk_bf16_f32 %0, %1, %2" : "=v"(r) : "v"(lo), "v"(hi));
    return r;
}

// residual v - float(bf16_hi(v)), where pk holds the packed hi pair
__device__ __forceinline__ float lo_of(float v, unsigned pk, bool hi_half) {
    const float h = __uint_as_float(hi_half ? (pk & 0xFFFF0000u) : (pk << 16));
    return v - h;
}

__global__ __launch_bounds__(BLOCK_THREADS) void dln_mfma(
    const float* __restrict__ x,
    const float* __restrict__ W1,  const float* __restrict__ b1,
    const float* __restrict__ W2,  const float* __restrict__ b2,
    const float* __restrict__ WLd, const float* __restrict__ bLd,
    const float* __restrict__ WLo, const float* __restrict__ bLo,
    float* __restrict__ out, int ngroups)
{
    __shared__ __align__(16) unsigned short h1s[4][8][64][8];   // 32 KiB

    const int tid  = threadIdx.x;
    const int lane = tid & 63;
    const int wv   = tid >> 6;          // wave id 0..3
    const int quad = lane >> 4;         // 0..3
    const int c    = lane & 15;         // 0..15

    // ---- first x load in flight before the weight preamble ----------------
    int grp = blockIdx.x;
    float4 qnext = ((const float4*)x)[grp * ROWS_PER_GROUP + tid];

    // ---- layer-2 A fragments from nu-permuted W2 rows + permuted b2 -------
    bf16x8 afrag[4][2];
    f32x4 b2v[4];
#pragma unroll
    for (int mt = 0; mt < 4; ++mt) {
        // A[m=c] = W2 row nu(mt,c)
        const int nu = 32 * (mt >> 1) + 8 * (c >> 2) + 4 * (mt & 1) + (c & 3);
        const float* wr = W2 + nu * 64 + 8 * quad;
#pragma unroll
        for (int s = 0; s < 2; ++s) {
            const float4 f0 = *(const float4*)(wr + 32 * s);
            const float4 f1 = *(const float4*)(wr + 32 * s + 4);
            uint4 u;
            u.x = cvt_pk_bf16(f0.x, f0.y);
            u.y = cvt_pk_bf16(f0.z, f0.w);
            u.z = cvt_pk_bf16(f1.x, f1.y);
            u.w = cvt_pk_bf16(f1.z, f1.w);
            afrag[mt][s] = __builtin_bit_cast(bf16x8, u);
        }
        // b2v[mt][r] = b2[nu(mt, 4*quad + r)] (contiguous in r)
        b2v[mt] = *(const f32x4*)(b2 + 32 * (mt >> 1) + 4 * (mt & 1) + 8 * quad);
    }

    // ---- head A fragments: rows {WLd0, WLd1, WLo, 0...}, hi/lo split ------
    bf16x8 hA[2][2];    // [k-chunk s][hi=0 / lo=1]
    {
        const float* hw = (c == 0) ? WLd : (c == 1) ? (WLd + 64) : WLo;
#pragma unroll
        for (int s = 0; s < 2; ++s) {
            uint4 uh = make_uint4(0u, 0u, 0u, 0u);
            uint4 ul = make_uint4(0u, 0u, 0u, 0u);
            if (c < 3) {
                const float* p = hw + 32 * s + 8 * quad;
                const float4 f0 = *(const float4*)(p);
                const float4 f1 = *(const float4*)(p + 4);
                uh.x = cvt_pk_bf16(f0.x, f0.y);
                uh.y = cvt_pk_bf16(f0.z, f0.w);
                uh.z = cvt_pk_bf16(f1.x, f1.y);
                uh.w = cvt_pk_bf16(f1.z, f1.w);
                ul.x = cvt_pk_bf16(lo_of(f0.x, uh.x, false), lo_of(f0.y, uh.x, true));
                ul.y = cvt_pk_bf16(lo_of(f0.z, uh.y, false), lo_of(f0.w, uh.y, true));
                ul.z = cvt_pk_bf16(lo_of(f1.x, uh.z, false), lo_of(f1.y, uh.z, true));
                ul.w = cvt_pk_bf16(lo_of(f1.z, uh.w, false), lo_of(f1.w, uh.w, true));
            }
            hA[s][0] = __builtin_bit_cast(bf16x8, uh);
            hA[s][1] = __builtin_bit_cast(bf16x8, ul);
        }
    }
    // head-accumulator bias init: C rows m=0,1,2 get bLd0, bLd1, bLo
    const float bld0 = bLd[0];
    const float bld1 = bLd[1];
    const float blo0 = bLo[0];
    const f32x4 hinit = (quad == 0) ? (f32x4){bld0, bld1, blo0, 0.0f}
                                    : (f32x4){0.0f, 0.0f, 0.0f, 0.0f};

    for (; grp < ngroups; grp += (int)gridDim.x) {
        const float4 qv = qnext;
        const int gn = grp + (int)gridDim.x;
        if (gn < ngroups)                              // uniform branch
            qnext = ((const float4*)x)[gn * ROWS_PER_GROUP + tid];
        const int wbase = grp * ROWS_PER_GROUP + wv * 64;

        // ---- phase 1: h1 = lrelu(q@W1^T + b1), bf16 -> LDS (own slot) ----
#pragma unroll
        for (int ch = 0; ch < 8; ++ch) {        // chunk ch holds k=8ch..8ch+7
            unsigned up[4];
#pragma unroll
            for (int p = 0; p < 4; ++p) {
                float h[2];
#pragma unroll
                for (int e = 0; e < 2; ++e) {
                    const int j = ch * 8 + p * 2 + e;
                    float a = b1[j];
                    a = fmaf(qv.x, W1[4 * j + 0], a);
                    a = fmaf(qv.y, W1[4 * j + 1], a);
                    a = fmaf(qv.z, W1[4 * j + 2], a);
                    a = fmaf(qv.w, W1[4 * j + 3], a);
                    h[e] = lrelu(a);
                }
                up[p] = cvt_pk_bf16(h[0], h[1]);
            }
            *(uint4*)&h1s[wv][ch][lane][0] = make_uint4(up[0], up[1], up[2], up[3]);
        }
        // No barrier: this wave reads only rows it wrote; per-wave DS ops
        // execute in order (also makes buffer reuse across groups safe).

        // ---- phase 2: layer-2 MFMA -> pack h2 -> head MFMA ---------------
#pragma unroll
        for (int it = 0; it < 4; ++it) {            // 16 batch rows / iter
            const bf16x8 bf0 = *(const bf16x8*)&h1s[wv][quad][it * 16 + c][0];
            const bf16x8 bf1 = *(const bf16x8*)&h1s[wv][4 + quad][it * 16 + c][0];

            // C[m=4q+r][n=c] = h2pre[row c][neuron nu(mt,4q+r)]
            uint4 u0, u1;
#pragma unroll
            for (int mt = 0; mt < 4; ++mt) {
                f32x4 acc = b2v[mt];                // permuted bias pre-load
                acc = __builtin_amdgcn_mfma_f32_16x16x32_bf16(afrag[mt][0], bf0, acc, 0, 0, 0);
                acc = __builtin_amdgcn_mfma_f32_16x16x32_bf16(afrag[mt][1], bf1, acc, 0, 0, 0);
                const f32x2 hlo = lrelu2((f32x2){acc[0], acc[1]});
                const f32x2 hhi = lrelu2((f32x2){acc[2], acc[3]});
                const unsigned pa = cvt_pk_bf16(hlo[0], hlo[1]);
                const unsigned pb = cvt_pk_bf16(hhi[0], hhi[1]);
                // nu makes packed h2 land with neuron k in k-slot k:
                // mt0 -> u0.x/.y (k=8q+0..3), mt1 -> u0.z/.w (k=8q+4..7)
                // mt2 -> u1.x/.y (k=32+8q+0..3), mt3 -> u1.z/.w (k=32+8q+4..7)
                if (mt == 0)      { u0.x = pa; u0.y = pb; }
                else if (mt == 1) { u0.z = pa; u0.w = pb; }
                else if (mt == 2) { u1.x = pa; u1.y = pb; }
                else              { u1.z = pa; u1.w = pb; }
            }
            const bf16x8 bh0 = __builtin_bit_cast(bf16x8, u0);
            const bf16x8 bh1 = __builtin_bit_cast(bf16x8, u1);

            // heads: C[m][n=row] for m = {Ld0, Ld1, Lo}; hi/lo-split A
            f32x4 hacc = hinit;
            hacc = __builtin_amdgcn_mfma_f32_16x16x32_bf16(hA[0][0], bh0, hacc, 0, 0, 0);
            hacc = __builtin_amdgcn_mfma_f32_16x16x32_bf16(hA[0][1], bh0, hacc, 0, 0, 0);
            hacc = __builtin_amdgcn_mfma_f32_16x16x32_bf16(hA[1][0], bh1, hacc, 0, 0, 0);
            hacc = __builtin_amdgcn_mfma_f32_16x16x32_bf16(hA[1][1], bh1, hacc, 0, 0, 0);

            // quad-0 lanes hold rows m=0,1,2 for batch row it*16+c
            if (quad == 0) {
                const float ld0 = softplus(hacc[0]);
                const float ld1 = softplus(hacc[1]);
                const float lo  = hacc[2];
                float4 o;
                o.x = fmaf(ld0, ld0, 1e-9f);                  // H00
                o.y = ld0 * lo;                               // H01
                o.z = o.y;                                    // H10
                o.w = fmaf(lo, lo, fmaf(ld1, ld1, 1e-9f));    // H11
                reinterpret_cast<float4*>(out)[wbase + it * 16 + c] = o;
            }
        }
    }
}

// ---- scalar fallback for tail rows (nrows % 256) --------------------------
__global__ __launch_bounds__(256) void dln_tail(
    const float* __restrict__ x,
    const float* __restrict__ W1,  const float* __restrict__ b1,
    const float* __restrict__ W2,  const float* __restrict__ b2,
    const float* __restrict__ WLd, const float* __restrict__ bLd,
    const float* __restrict__ WLo, const float* __restrict__ bLo,
    float* __restrict__ out, int row0, int nrows)
{
    const int row = row0 + blockIdx.x * 256 + threadIdx.x;
    if (row >= nrows) return;
    const float4 qv = reinterpret_cast<const float4*>(x)[row];
    float h1[64];
#pragma unroll
    for (int j = 0; j < 64; ++j) {
        float a = b1[j];
        a = fmaf(qv.x, W1[4 * j + 0], a);
        a = fmaf(qv.y, W1[4 * j + 1], a);
        a = fmaf(qv.z, W1[4 * j + 2], a);
        a = fmaf(qv.w, W1[4 * j + 3], a);
        h1[j] = lrelu(a);
    }
    float ld0 = bLd[0], ld1 = bLd[1], lo = bLo[0];
#pragma unroll 4
    for (int j = 0; j < 64; ++j) {
        float a0 = b2[j], a1 = 0.0f;
        const float* w = W2 + 64 * j;
#pragma unroll
        for (int k = 0; k < 64; k += 2) {
            a0 = fmaf(h1[k],     w[k],     a0);
            a1 = fmaf(h1[k + 1], w[k + 1], a1);
        }
        const float a = lrelu(a0 + a1);
        ld0 = fmaf(a, WLd[j],      ld0);
        ld1 = fmaf(a, WLd[64 + j], ld1);
        lo  = fmaf(a, WLo[j],      lo);
    }
    ld0 = softplus(ld0);
    ld1 = softplus(ld1);
    float4 o;
    o.x = fmaf(ld0, ld0, 1e-9f);
    o.y = ld0 * lo;
    o.z = o.y;
    o.w = fmaf(lo, lo, fmaf(ld1, ld1, 1e-9f));
    reinterpret_cast<float4*>(out)[row] = o;
}

extern "C" void kernel_launch(void* const* d_in, const int* in_sizes, int n_in,
                              void* d_out, int out_size, void* d_ws, size_t ws_size,
                              hipStream_t stream)
{
    const float* x   = (const float*)d_in[0];
    const float* W1  = (const float*)d_in[1];
    const float* b1  = (const float*)d_in[2];
    const float* W2  = (const float*)d_in[3];
    const float* b2  = (const float*)d_in[4];
    const float* WLd = (const float*)d_in[5];
    const float* bLd = (const float*)d_in[6];
    const float* WLo = (const float*)d_in[7];
    const float* bLo = (const float*)d_in[8];
    float* out = (float*)d_out;

    const int nrows   = in_sizes[0] / 4;            // x is (nrows, 4) fp32
    const int ngroups = nrows / ROWS_PER_GROUP;
    const int nfull   = ngroups * ROWS_PER_GROUP;
    const int rem     = nrows - nfull;

    if (ngroups > 0) {
        const int grid = (ngroups < GRID_BLOCKS) ? ngroups : GRID_BLOCKS;
        dln_mfma<<<grid, BLOCK_THREADS, 0, stream>>>(
            x, W1, b1, W2, b2, WLd, bLd, WLo, bLo, out, ngroups);
    }
    if (rem > 0)
        dln_tail<<<(rem + 255) / 256, 256, 0, stream>>>(
            x, W1, b1, W2, b2, WLd, bLd, WLo, bLo, out, nfull, nrows);
}